// Round 1
// baseline (56.108 us; speedup 1.0000x reference)
//
#include <hip/hip_runtime.h>
#include <hip/hip_bf16.h>
#include <math.h>

// Problem: B=16, K=256, D=128, H=64
//   hi[b,k,h] = particles[b,k,:] @ W1[:D, h] + b1[h]   (b1 folded here)
//   hj[b,k,h] = particles[b,k,:] @ W1[D:, h]
//   sd[b,i,j] = sum_h gelu(hi[b,i,h] + hj[b,j,h]) * W2[h] + b2
//   loss = mean((sd - true_dist)^2)
// Output: [sd flattened (16*256*256 floats)] [loss (1 float)]

#define Bn 16
#define Kn 256
#define Dn 128
#define Hn 64

// ---------------- Kernel A: hi/hj precompute ----------------
// grid: (B*K)/16 = 256 blocks, 256 threads. Each block: 16 rows.
// W1 staged in LDS in two halves (32 KB each) to stay under static-LDS limits.
__global__ __launch_bounds__(256) void kA(const float* __restrict__ particles,
                                          const float* __restrict__ W1,
                                          const float* __restrict__ b1,
                                          float* __restrict__ hi,
                                          float* __restrict__ hj) {
    __shared__ float w1s[Dn * Hn];      // 32 KB (one half of W1)
    __shared__ float ps[16][Dn];        // 8 KB
    const int tid = threadIdx.x;
    const int row0 = blockIdx.x * 16;

    for (int idx = tid; idx < 16 * Dn; idx += 256)
        ps[idx >> 7][idx & 127] = particles[row0 * Dn + idx];

    const int h = tid & 63;
    const int sub = tid >> 6;          // wave id 0..3

    for (int half = 0; half < 2; ++half) {
        __syncthreads();
        for (int idx = tid; idx < Dn * Hn; idx += 256)
            w1s[idx] = W1[half * (Dn * Hn) + idx];
        __syncthreads();
        float* __restrict__ dst = (half == 0) ? hi : hj;
        const float init = (half == 0) ? b1[h] : 0.0f;
        for (int rr = 0; rr < 4; ++rr) {
            const int r = sub * 4 + rr;
            float a = init;
#pragma unroll 8
            for (int d = 0; d < Dn; ++d)
                a = fmaf(ps[r][d], w1s[d * Hn + h], a);
            dst[(row0 + r) * Hn + h] = a;
        }
    }
}

// ---------------- Kernel B: main pairwise kernel ----------------
// grid: (K/16, K/16, B) blocks of 256 threads; thread = (ti = tid>>4, tj = tid&15).
__global__ __launch_bounds__(256) void kB(const float* __restrict__ hi,
                                          const float* __restrict__ hj,
                                          const float* __restrict__ positions,
                                          const float* __restrict__ W2,
                                          const float* __restrict__ b2,
                                          float* __restrict__ out,
                                          float* __restrict__ partials) {
    __shared__ float shi[16][65];      // pad 65: conflict-free shi[ti][h] / shj[tj][h]
    __shared__ float shj[16][65];
    __shared__ float w2s[Hn];
    __shared__ float pix[16], piy[16], pjx[16], pjy[16];
    __shared__ float wsum[4];

    const int jt = blockIdx.x, it = blockIdx.y, b = blockIdx.z;
    const int tid = threadIdx.x;

    if (tid < Hn) w2s[tid] = W2[tid];
    for (int idx = tid; idx < 16 * Hn; idx += 256) {
        const int r = idx >> 6, c = idx & 63;
        shi[r][c] = hi[((b * Kn) + it * 16 + r) * Hn + c];
        shj[r][c] = hj[((b * Kn) + jt * 16 + r) * Hn + c];
    }
    if (tid < 16) {
        pix[tid] = positions[((b * Kn) + it * 16 + tid) * 2 + 0];
        piy[tid] = positions[((b * Kn) + it * 16 + tid) * 2 + 1];
        pjx[tid] = positions[((b * Kn) + jt * 16 + tid) * 2 + 0];
        pjy[tid] = positions[((b * Kn) + jt * 16 + tid) * 2 + 1];
    }
    const float bb = b2[0];
    __syncthreads();

    const int ti = tid >> 4, tj = tid & 15;

    float acc = 0.0f;
#pragma unroll 8
    for (int h = 0; h < Hn; ++h) {
        const float x = shi[ti][h] + shj[tj][h];
        // exact GELU: 0.5*x*(1+erf(x/sqrt(2)))
        const float g = 0.5f * x * (1.0f + erff(x * 0.70710678118654752f));
        acc = fmaf(g, w2s[h], acc);
    }
    const float sd = acc + bb;

    const float dx = pix[ti] - pjx[tj];
    const float dy = piy[ti] - pjy[tj];
    const float d2 = dx * dx + dy * dy;
    const float td = (d2 > 0.0f) ? sqrtf(d2) : 0.0f;

    const int i = it * 16 + ti, j = jt * 16 + tj;
    out[((b * Kn) + i) * Kn + j] = sd;

    // deterministic block reduce of squared error
    float v = (sd - td) * (sd - td);
#pragma unroll
    for (int off = 32; off > 0; off >>= 1) v += __shfl_down(v, off);
    if ((tid & 63) == 0) wsum[tid >> 6] = v;
    __syncthreads();
    if (tid == 0) {
        const int bid = (b * gridDim.y + it) * gridDim.x + jt;
        partials[bid] = (wsum[0] + wsum[1]) + (wsum[2] + wsum[3]);
    }
}

// ---------------- Kernel C: final loss reduction (deterministic order) ----------------
__global__ __launch_bounds__(256) void kC(const float* __restrict__ partials,
                                          float* __restrict__ loss_out) {
    __shared__ float s[256];
    const int tid = threadIdx.x;
    float v = 0.0f;
#pragma unroll
    for (int k = 0; k < 16; ++k) v += partials[tid + k * 256];
    s[tid] = v;
    __syncthreads();
    for (int off = 128; off > 0; off >>= 1) {
        if (tid < off) s[tid] += s[tid + off];
        __syncthreads();
    }
    if (tid == 0)
        loss_out[0] = s[0] * (1.0f / (float)(Bn * Kn * Kn));
}

extern "C" void kernel_launch(void* const* d_in, const int* in_sizes, int n_in,
                              void* d_out, int out_size, void* d_ws, size_t ws_size,
                              hipStream_t stream) {
    const float* particles = (const float*)d_in[0];
    const float* positions = (const float*)d_in[1];
    const float* W1        = (const float*)d_in[2];
    const float* b1        = (const float*)d_in[3];
    const float* W2        = (const float*)d_in[4];
    const float* b2        = (const float*)d_in[5];

    float* out = (float*)d_out;                       // [B*K*K] sd, then [1] loss
    float* ws  = (float*)d_ws;
    float* hi       = ws;                             // B*K*H = 262144 floats
    float* hj       = ws + Bn * Kn * Hn;              // 262144 floats
    float* partials = ws + 2 * Bn * Kn * Hn;          // 4096 floats

    kA<<<dim3((Bn * Kn) / 16), dim3(256), 0, stream>>>(particles, W1, b1, hi, hj);
    kB<<<dim3(Kn / 16, Kn / 16, Bn), dim3(256), 0, stream>>>(hi, hj, positions, W2, b2,
                                                             out, partials);
    kC<<<dim3(1), dim3(256), 0, stream>>>(partials, out + (size_t)Bn * Kn * Kn);
}

// Round 2
// 37.135 us; speedup vs baseline: 1.5109x; 1.5109x over previous
//
#include <hip/hip_runtime.h>
#include <hip/hip_bf16.h>
#include <math.h>

// Problem: B=16, K=256, D=128, H=64
//   hi[b,k,h] = particles[b,k,:] @ W1[:D, h] + b1[h]   (b1 folded here)
//   hj[b,k,h] = particles[b,k,:] @ W1[D:, h]
//   sd[b,i,j] = sum_h gelu(hi[b,i,h] + hj[b,j,h]) * W2[h] + b2
//   loss = mean((sd - true_dist)^2)
// Output: [sd flattened (16*256*256 floats)] [loss (1 float)]

#define Bn 16
#define Kn 256
#define Dn 128
#define Hn 64

// Fast GELU (tanh form), max abs deviation from exact-erf GELU ~5e-4:
//   gelu(x) = 0.5x(1+tanh(0.79788456(x+0.044715x^3))) = x / (1 + e^{-2y})
//           = x * rcp(1 + exp2(-2.3022082 * x * (1 + 0.044715 x^2)))
__device__ __forceinline__ float gelu_fast(float x) {
    float x2 = x * x;
    float t  = fmaf(0.044715f, x2, 1.0f);
    float z  = x * t;
    float e  = __builtin_amdgcn_exp2f(z * -2.3022082f);
    float r  = __builtin_amdgcn_rcpf(1.0f + e);
    return x * r;   // inf-safe: e=inf -> r=0 -> g=0; e=0 -> r=1 -> g=x
}

// ---------------- Kernel A: hi/hj precompute ----------------
// 256 blocks x 256 threads; block handles 16 rows. Both W1 halves staged in LDS.
// thread = (r = tid>>4, h0 = (tid&15)*4): 8 accumulators (4 h x {i,j}).
__global__ __launch_bounds__(256) void kA(const float* __restrict__ particles,
                                          const float* __restrict__ W1,
                                          const float* __restrict__ b1,
                                          float* __restrict__ hi,
                                          float* __restrict__ hj) {
    __shared__ __align__(16) float w1a[Dn * Hn];   // 32 KB  W1[:128]
    __shared__ __align__(16) float w1b[Dn * Hn];   // 32 KB  W1[128:]
    __shared__ __align__(16) float ps[16][Dn];     // 8 KB
    __shared__ __align__(16) float b1s[Hn];

    const int tid = threadIdx.x;
    const int row0 = blockIdx.x * 16;

    for (int idx = tid; idx < (Dn * Hn) / 4; idx += 256) {
        ((float4*)w1a)[idx] = ((const float4*)W1)[idx];
        ((float4*)w1b)[idx] = ((const float4*)(W1 + Dn * Hn))[idx];
    }
    for (int idx = tid; idx < (16 * Dn) / 4; idx += 256)
        ((float4*)&ps[0][0])[idx] = ((const float4*)(particles + row0 * Dn))[idx];
    if (tid < Hn / 4)
        ((float4*)b1s)[tid] = ((const float4*)b1)[tid];
    __syncthreads();

    const int r  = tid >> 4;
    const int h0 = (tid & 15) * 4;

    float4 ai = {0.f, 0.f, 0.f, 0.f};
    float4 aj = {0.f, 0.f, 0.f, 0.f};
#pragma unroll 8
    for (int d = 0; d < Dn; ++d) {
        const float p  = ps[r][d];
        const float4 wa = *(const float4*)&w1a[d * Hn + h0];
        const float4 wb = *(const float4*)&w1b[d * Hn + h0];
        ai.x = fmaf(p, wa.x, ai.x); ai.y = fmaf(p, wa.y, ai.y);
        ai.z = fmaf(p, wa.z, ai.z); ai.w = fmaf(p, wa.w, ai.w);
        aj.x = fmaf(p, wb.x, aj.x); aj.y = fmaf(p, wb.y, aj.y);
        aj.z = fmaf(p, wb.z, aj.z); aj.w = fmaf(p, wb.w, aj.w);
    }
    const float4 bb = *(const float4*)&b1s[h0];
    ai.x += bb.x; ai.y += bb.y; ai.z += bb.z; ai.w += bb.w;

    *(float4*)&hi[(row0 + r) * Hn + h0] = ai;
    *(float4*)&hj[(row0 + r) * Hn + h0] = aj;
}

// ---------------- Kernel B: main pairwise kernel ----------------
// grid (K/16, K/16, B), 256 threads; thread (ti=tid>>4, tj=tid&15), 1 output,
// h-loop vectorized by float4. Rows padded to 68 floats: 16B-aligned, 2-way bank (free).
__global__ __launch_bounds__(256) void kB(const float* __restrict__ hi,
                                          const float* __restrict__ hj,
                                          const float* __restrict__ positions,
                                          const float* __restrict__ W2,
                                          const float* __restrict__ b2,
                                          float* __restrict__ out,
                                          float* __restrict__ partials) {
    __shared__ __align__(16) float shi[16][68];
    __shared__ __align__(16) float shj[16][68];
    __shared__ __align__(16) float w2s[Hn];
    __shared__ float pix[16], piy[16], pjx[16], pjy[16];
    __shared__ float wsum[4];

    const int jt = blockIdx.x, it = blockIdx.y, b = blockIdx.z;
    const int tid = threadIdx.x;

    {   // stage hi/hj tiles: 16 rows x 64 floats = 256 float4 each; 1 per thread
        const int r = tid >> 4, c4 = (tid & 15) * 4;
        *(float4*)&shi[r][c4] = *(const float4*)&hi[((b * Kn) + it * 16 + r) * Hn + c4];
        *(float4*)&shj[r][c4] = *(const float4*)&hj[((b * Kn) + jt * 16 + r) * Hn + c4];
    }
    if (tid < Hn / 4)
        ((float4*)w2s)[tid] = ((const float4*)W2)[tid];
    if (tid < 16) {
        pix[tid] = positions[((b * Kn) + it * 16 + tid) * 2 + 0];
        piy[tid] = positions[((b * Kn) + it * 16 + tid) * 2 + 1];
        pjx[tid] = positions[((b * Kn) + jt * 16 + tid) * 2 + 0];
        pjy[tid] = positions[((b * Kn) + jt * 16 + tid) * 2 + 1];
    }
    const float bb = b2[0];
    __syncthreads();

    const int ti = tid >> 4, tj = tid & 15;

    float acc = 0.0f;
#pragma unroll
    for (int h = 0; h < Hn; h += 4) {
        const float4 a = *(const float4*)&shi[ti][h];
        const float4 c = *(const float4*)&shj[tj][h];
        const float4 w = *(const float4*)&w2s[h];
        acc = fmaf(gelu_fast(a.x + c.x), w.x, acc);
        acc = fmaf(gelu_fast(a.y + c.y), w.y, acc);
        acc = fmaf(gelu_fast(a.z + c.z), w.z, acc);
        acc = fmaf(gelu_fast(a.w + c.w), w.w, acc);
    }
    const float sd = acc + bb;

    const float dx = pix[ti] - pjx[tj];
    const float dy = piy[ti] - pjy[tj];
    const float d2 = dx * dx + dy * dy;
    const float td = (d2 > 0.0f) ? sqrtf(d2) : 0.0f;

    const int i = it * 16 + ti, j = jt * 16 + tj;
    out[((b * Kn) + i) * Kn + j] = sd;

    // deterministic block reduce of squared error
    float v = (sd - td) * (sd - td);
#pragma unroll
    for (int off = 32; off > 0; off >>= 1) v += __shfl_down(v, off);
    if ((tid & 63) == 0) wsum[tid >> 6] = v;
    __syncthreads();
    if (tid == 0) {
        const int bid = (b * gridDim.y + it) * gridDim.x + jt;
        partials[bid] = (wsum[0] + wsum[1]) + (wsum[2] + wsum[3]);
    }
}

// ---------------- Kernel C: final loss reduction (deterministic order) ----------------
__global__ __launch_bounds__(256) void kC(const float* __restrict__ partials,
                                          float* __restrict__ loss_out) {
    __shared__ float s[256];
    const int tid = threadIdx.x;
    float v = 0.0f;
#pragma unroll
    for (int k = 0; k < 16; ++k) v += partials[tid + k * 256];
    s[tid] = v;
    __syncthreads();
    for (int off = 128; off > 0; off >>= 1) {
        if (tid < off) s[tid] += s[tid + off];
        __syncthreads();
    }
    if (tid == 0)
        loss_out[0] = s[0] * (1.0f / (float)(Bn * Kn * Kn));
}

extern "C" void kernel_launch(void* const* d_in, const int* in_sizes, int n_in,
                              void* d_out, int out_size, void* d_ws, size_t ws_size,
                              hipStream_t stream) {
    const float* particles = (const float*)d_in[0];
    const float* positions = (const float*)d_in[1];
    const float* W1        = (const float*)d_in[2];
    const float* b1        = (const float*)d_in[3];
    const float* W2        = (const float*)d_in[4];
    const float* b2        = (const float*)d_in[5];

    float* out = (float*)d_out;                       // [B*K*K] sd, then [1] loss
    float* ws  = (float*)d_ws;
    float* hi       = ws;                             // B*K*H floats
    float* hj       = ws + Bn * Kn * Hn;
    float* partials = ws + 2 * Bn * Kn * Hn;          // 4096 floats

    kA<<<dim3((Bn * Kn) / 16), dim3(256), 0, stream>>>(particles, W1, b1, hi, hj);
    kB<<<dim3(Kn / 16, Kn / 16, Bn), dim3(256), 0, stream>>>(hi, hj, positions, W2, b2,
                                                             out, partials);
    kC<<<dim3(1), dim3(256), 0, stream>>>(partials, out + (size_t)Bn * Kn * Kn);
}

// Round 6
// 30.996 us; speedup vs baseline: 1.8102x; 1.1980x over previous
//
#include <hip/hip_runtime.h>
#include <hip/hip_bf16.h>
#include <math.h>

// Problem: B=16, K=256, D=128, H=64
//   hi[b,k,h] = particles[b,k,:] @ W1[:D, h] + b1[h]   (b1 folded here)
//   hj[b,k,h] = particles[b,k,:] @ W1[D:, h]
//   sd[b,i,j] = sum_h gelu(hi[b,i,h] + hj[b,j,h]) * W2[h] + b2
//   loss = mean((sd - true_dist)^2)
// Output: [sd flattened (16*256*256 floats)] [loss (1 float)]

#define Bn 16
#define Kn 256
#define Dn 128
#define Hn 64

typedef float f32x2 __attribute__((ext_vector_type(2)));
typedef int   i32x2 __attribute__((ext_vector_type(2)));

// Trans-free fast GELU on 2 lanes of packed f32.
//   gelu(x) ~= x * sigmoid(2.3022082*x*(1+0.044715 x^2))   (tanh-form identity)
//   exp2 via Schraudolph bit-trick (+-3% rel -> dgelu <= ~4e-3)
//   rcp  via magic-constant + 1 Newton step (~0.25% rel)
// All ops are v_pk_fma/add/mul-capable except 2x v_cvt_i32 and 2x v_sub (full rate).
__device__ __forceinline__ void gelu_dot2(f32x2 a, f32x2 c, f32x2 w, f32x2& acc) {
    f32x2 x  = a + c;
    f32x2 x2 = x * x;
    // t = -2.3022082*x*(1+0.044715x^2) = x*(-2.3022082 - 0.10294828 x^2)
    f32x2 t1 = __builtin_elementwise_fma(x2, (f32x2)(-0.10294828f), (f32x2)(-2.3022082f));
    f32x2 t  = x * t1;
    // e ~= 2^t : bits = t*2^23 + (127 - 0.0436)*2^23
    f32x2 u  = __builtin_elementwise_fma(t, (f32x2)8388608.0f, (f32x2)1064987473.0f);
    i32x2 iu = __builtin_convertvector(u, i32x2);          // u > 0 always (t >= -37)
    f32x2 e  = __builtin_bit_cast(f32x2, iu);
    f32x2 d  = e + 1.0f;                                   // d in (1, inf)
    // r ~= 1/d : magic + 1 NR
    i32x2 id = __builtin_bit_cast(i32x2, d);
    i32x2 ir = 0x7EF311C3 - id;
    f32x2 r0 = __builtin_bit_cast(f32x2, ir);
    f32x2 q  = __builtin_elementwise_fma(-d, r0, (f32x2)2.0f);
    f32x2 r  = r0 * q;
    f32x2 g  = x * r;                                      // x * sigmoid
    acc = __builtin_elementwise_fma(g, w, acc);
}

// ---------------- Kernel A: hi/hj precompute ----------------
__global__ __launch_bounds__(256) void kA(const float* __restrict__ particles,
                                          const float* __restrict__ W1,
                                          const float* __restrict__ b1,
                                          float* __restrict__ hi,
                                          float* __restrict__ hj) {
    __shared__ __align__(16) float w1a[Dn * Hn];   // 32 KB  W1[:128]
    __shared__ __align__(16) float w1b[Dn * Hn];   // 32 KB  W1[128:]
    __shared__ __align__(16) float ps[16][Dn];     // 8 KB
    __shared__ __align__(16) float b1s[Hn];

    const int tid = threadIdx.x;
    const int row0 = blockIdx.x * 16;

    for (int idx = tid; idx < (Dn * Hn) / 4; idx += 256) {
        ((float4*)w1a)[idx] = ((const float4*)W1)[idx];
        ((float4*)w1b)[idx] = ((const float4*)(W1 + Dn * Hn))[idx];
    }
    for (int idx = tid; idx < (16 * Dn) / 4; idx += 256)
        ((float4*)&ps[0][0])[idx] = ((const float4*)(particles + row0 * Dn))[idx];
    if (tid < Hn / 4)
        ((float4*)b1s)[tid] = ((const float4*)b1)[tid];
    __syncthreads();

    const int r  = tid >> 4;
    const int h0 = (tid & 15) * 4;

    float4 ai = {0.f, 0.f, 0.f, 0.f};
    float4 aj = {0.f, 0.f, 0.f, 0.f};
#pragma unroll 8
    for (int d = 0; d < Dn; ++d) {
        const float p  = ps[r][d];
        const float4 wa = *(const float4*)&w1a[d * Hn + h0];
        const float4 wb = *(const float4*)&w1b[d * Hn + h0];
        ai.x = fmaf(p, wa.x, ai.x); ai.y = fmaf(p, wa.y, ai.y);
        ai.z = fmaf(p, wa.z, ai.z); ai.w = fmaf(p, wa.w, ai.w);
        aj.x = fmaf(p, wb.x, aj.x); aj.y = fmaf(p, wb.y, aj.y);
        aj.z = fmaf(p, wb.z, aj.z); aj.w = fmaf(p, wb.w, aj.w);
    }
    const float4 bb = *(const float4*)&b1s[h0];
    ai.x += bb.x; ai.y += bb.y; ai.z += bb.z; ai.w += bb.w;

    *(float4*)&hi[(row0 + r) * Hn + h0] = ai;
    *(float4*)&hj[(row0 + r) * Hn + h0] = aj;
}

// ---------------- Kernel B: main pairwise kernel ----------------
// grid (K/16, K/16, B), 256 threads; thread (ti=tid>>4, tj=tid&15), 1 output.
__global__ __launch_bounds__(256) void kB(const float* __restrict__ hi,
                                          const float* __restrict__ hj,
                                          const float* __restrict__ positions,
                                          const float* __restrict__ W2,
                                          const float* __restrict__ b2,
                                          float* __restrict__ out,
                                          float* __restrict__ partials) {
    __shared__ __align__(16) float shi[16][68];
    __shared__ __align__(16) float shj[16][68];
    __shared__ float pix[16], piy[16], pjx[16], pjy[16];
    __shared__ float wsum[4];

    const int jt = blockIdx.x, it = blockIdx.y, b = blockIdx.z;
    const int tid = threadIdx.x;

    {   // stage hi/hj tiles: 16 rows x 64 floats = 256 float4 each; 1 per thread
        const int r = tid >> 4, c4 = (tid & 15) * 4;
        *(float4*)&shi[r][c4] = *(const float4*)&hi[((b * Kn) + it * 16 + r) * Hn + c4];
        *(float4*)&shj[r][c4] = *(const float4*)&hj[((b * Kn) + jt * 16 + r) * Hn + c4];
    }
    if (tid < 16) {
        pix[tid] = positions[((b * Kn) + it * 16 + tid) * 2 + 0];
        piy[tid] = positions[((b * Kn) + it * 16 + tid) * 2 + 1];
        pjx[tid] = positions[((b * Kn) + jt * 16 + tid) * 2 + 0];
        pjy[tid] = positions[((b * Kn) + jt * 16 + tid) * 2 + 1];
    }
    const float bb = b2[0];
    __syncthreads();

    const int ti = tid >> 4, tj = tid & 15;

    // W2 via uniform index -> scalar loads into SGPRs
    const f32x2* __restrict__ W2v = (const f32x2*)W2;

    f32x2 accA = {0.f, 0.f}, accB = {0.f, 0.f};
#pragma unroll
    for (int h = 0; h < Hn; h += 4) {
        const float4 a = *(const float4*)&shi[ti][h];
        const float4 c = *(const float4*)&shj[tj][h];
        const f32x2 w0 = W2v[(h >> 1) + 0];
        const f32x2 w1 = W2v[(h >> 1) + 1];
        gelu_dot2((f32x2){a.x, a.y}, (f32x2){c.x, c.y}, w0, accA);
        gelu_dot2((f32x2){a.z, a.w}, (f32x2){c.z, c.w}, w1, accB);
    }
    const f32x2 accs = accA + accB;
    const float sd = accs.x + accs.y + bb;

    const float dx = pix[ti] - pjx[tj];
    const float dy = piy[ti] - pjy[tj];
    const float d2 = dx * dx + dy * dy;
    const float td = (d2 > 0.0f) ? sqrtf(d2) : 0.0f;

    const int i = it * 16 + ti, j = jt * 16 + tj;
    out[((b * Kn) + i) * Kn + j] = sd;

    // deterministic block reduce of squared error
    float v = (sd - td) * (sd - td);
#pragma unroll
    for (int off = 32; off > 0; off >>= 1) v += __shfl_down(v, off);
    if ((tid & 63) == 0) wsum[tid >> 6] = v;
    __syncthreads();
    if (tid == 0) {
        const int bid = (b * gridDim.y + it) * gridDim.x + jt;
        partials[bid] = (wsum[0] + wsum[1]) + (wsum[2] + wsum[3]);
    }
}

// ---------------- Kernel C: final loss reduction (deterministic order) ----------------
__global__ __launch_bounds__(256) void kC(const float* __restrict__ partials,
                                          float* __restrict__ loss_out) {
    __shared__ float s[256];
    const int tid = threadIdx.x;
    const float4* p4 = (const float4*)partials;
    float v = 0.0f;
#pragma unroll
    for (int k = 0; k < 4; ++k) {
        const float4 x = p4[tid + k * 256];
        v += (x.x + x.y) + (x.z + x.w);
    }
    s[tid] = v;
    __syncthreads();
    for (int off = 128; off > 0; off >>= 1) {
        if (tid < off) s[tid] += s[tid + off];
        __syncthreads();
    }
    if (tid == 0)
        loss_out[0] = s[0] * (1.0f / (float)(Bn * Kn * Kn));
}

extern "C" void kernel_launch(void* const* d_in, const int* in_sizes, int n_in,
                              void* d_out, int out_size, void* d_ws, size_t ws_size,
                              hipStream_t stream) {
    const float* particles = (const float*)d_in[0];
    const float* positions = (const float*)d_in[1];
    const float* W1        = (const float*)d_in[2];
    const float* b1        = (const float*)d_in[3];
    const float* W2        = (const float*)d_in[4];
    const float* b2        = (const float*)d_in[5];

    float* out = (float*)d_out;                       // [B*K*K] sd, then [1] loss
    float* ws  = (float*)d_ws;
    float* hi       = ws;                             // B*K*H floats
    float* hj       = ws + Bn * Kn * Hn;
    float* partials = ws + 2 * Bn * Kn * Hn;          // 4096 floats

    kA<<<dim3((Bn * Kn) / 16), dim3(256), 0, stream>>>(particles, W1, b1, hi, hj);
    kB<<<dim3(Kn / 16, Kn / 16, Bn), dim3(256), 0, stream>>>(hi, hj, positions, W2, b2,
                                                             out, partials);
    kC<<<dim3(1), dim3(256), 0, stream>>>(partials, out + (size_t)Bn * Kn * Kn);
}